// Round 11
// baseline (3415.356 us; speedup 1.0000x reference)
//
#include <hip/hip_runtime.h>
#include <hip/hip_fp16.h>

typedef _Float16 half2_t __attribute__((ext_vector_type(2)));
typedef _Float16 half8_t __attribute__((ext_vector_type(8)));
typedef float f32x4 __attribute__((ext_vector_type(4)));

struct __align__(16) H2x4 { half2_t h[4]; };
struct __align__(8)  H2x2 { half2_t h[2]; };

__device__ __forceinline__ float fdot2f(half2_t a, half2_t b, float c){
#if __has_builtin(__builtin_amdgcn_fdot2)
  return __builtin_amdgcn_fdot2(a, b, c, false);
#else
  return c + (float)a[0]*(float)b[0] + (float)a[1]*(float)b[1];
#endif
}

__device__ __forceinline__ float fast_exp2f(float x){
#if __has_builtin(__builtin_amdgcn_exp2f)
  return __builtin_amdgcn_exp2f(x);
#else
  return __expf(x*0.6931471805599453f);
#endif
}

// Pack two f32 -> packed f16 pair (v_cvt_pkrtz_f16_f32), bit-cast to our type.
__device__ __forceinline__ half2_t pkrtz(float lo, float hi){
  return __builtin_bit_cast(half2_t, __builtin_amdgcn_cvt_pkrtz(lo, hi));
}

// Pin a fragment into an ACCUMULATOR register (AGPR). On gfx950 the VGPR/AGPR
// file is unified and MFMA can read A directly from AGPRs, so this is a legal
// long-term home for loop-invariant weights (no per-step copies).
__device__ __forceinline__ void pinA(half8_t &x){ asm volatile("" : "+a"(x)); }

// MFMA with A sourced from AGPR, B from VGPR, C/D in VGPR (gfx950 mixed ops).
// NOTE: raw asm bypasses the compiler's MFMA hazard recognizer — callers MUST
// fence the accumulators before VALU reads (see accfence_* below).
__device__ __forceinline__ void mfma_av(f32x4 &c, const half8_t &a, const half8_t &b){
  asm("v_mfma_f32_16x16x32_f16 %0, %1, %2, %0"
      : "+v"(c) : "a"(a), "v"(b));
}

// Hazard fences with register dependencies: the "+v" ties force every MFMA
// writing these accs to precede the nops, and every read to follow them.
__device__ __forceinline__ void accfence_pre(f32x4 (&a0)[4], f32x4 (&a1)[4]){
  asm volatile("s_nop 1"                                   // VALU->MFMA SrcC
    : "+v"(a0[0]),"+v"(a0[1]),"+v"(a0[2]),"+v"(a0[3]),
      "+v"(a1[0]),"+v"(a1[1]),"+v"(a1[2]),"+v"(a1[3]));
}
__device__ __forceinline__ void accfence_post(f32x4 (&a0)[4], f32x4 (&a1)[4]){
  asm volatile("s_nop 7\n\ts_nop 7"                        // MFMA->VALU read
    : "+v"(a0[0]),"+v"(a0[1]),"+v"(a0[2]),"+v"(a0[3]),
      "+v"(a1[0]),"+v"(a1[1]),"+v"(a1[2]),"+v"(a1[3]));
}

// ---------------- prep: fp32 -> f16 casts ----------------
struct PrepArgs {
  const float* src[13];
  __half* dst[13];
  int n[13];
};
__global__ __launch_bounds__(256) void prep_cast_k(PrepArgs a){
  const int r = blockIdx.y;
  const int n = a.n[r];
  const float* __restrict__ s = a.src[r];
  __half* __restrict__ d = a.dst[r];
  for (int i = blockIdx.x*256 + threadIdx.x; i < n; i += gridDim.x*256)
    d[i] = __float2half(s[i]);
}

struct BiasArgs {
  const float *bih0f,*bhh0f,*bih0b,*bhh0b,*bih1f,*bhh1f,*bih1b,*bhh1b;
  const float *b1t1,*b1t2,*b2t1,*b2t2;
  float *b0,*b1,*bz,*by;
};
__global__ __launch_bounds__(256) void prep_bias_k(BiasArgs a){
  const int i = threadIdx.x;
  if (i < 256){
    a.b0[i]     = a.bih0f[i] + a.bhh0f[i];
    a.b0[256+i] = a.bih0b[i] + a.bhh0b[i];
    a.b1[i]     = a.bih1f[i] + a.bhh1f[i];
    a.b1[256+i] = a.bih1b[i] + a.bhh1b[i];
  }
  if (i < 128){ a.bz[i] = a.b1t1[i]; a.bz[128+i] = a.b1t2[i]; }
  if (i < 32){  a.by[i] = a.b2t1[i]; a.by[32+i]  = a.b2t2[i]; }
}

// ---------------- GEMM: C[m][n] = sum_k A[m][k]*B[n][k] + bias[n] ----------------
// B: f16 [N][K] row-major (weight layout).
// AMODE 0: A plain f16 [M][K] row-major.
// AMODE 1: A is rnn hblk layout: element (m,k) with m=b*2048+t, k=dir*256+r at
//          A[((dir*2048+t)*16 + b)*256 + r].
// MODE 0: out = pre layout for rnn_mfma_k:
//          idx = (((dir*2048+t)*64 + (row>>2))*16 + b)*4 + (row&3), dir=n>>8,row=n&255.
// MODE 1: out = z layout [m][256], relu.
template<int AMODE, int MODE>
__global__ __launch_bounds__(256,2) void gemm_nt_k(
    const __half* __restrict__ A, const __half* __restrict__ B,
    __half* __restrict__ C, const float* __restrict__ bias,
    int M, int N, int K)
{
  __shared__ __align__(16) _Float16 As[128*40];
  __shared__ __align__(16) _Float16 Bs[128*40];
  const int tid = threadIdx.x;
  const int wave = tid>>6, lane = tid&63;
  const int wr = wave>>1, wc = wave&1;
  const int lrow = lane&15, lk = lane>>4;
  const int m0 = blockIdx.x*128, n0 = blockIdx.y*128;
  f32x4 acc[4][4];
  #pragma unroll
  for (int i=0;i<4;i++)
    #pragma unroll
    for (int j=0;j<4;j++) acc[i][j] = (f32x4){0.f,0.f,0.f,0.f};

  for (int k0=0; k0<K; k0+=32){
    __syncthreads();
    #pragma unroll
    for (int i=0;i<2;i++){
      int idx = i*256 + tid;
      int row = idx>>2, ch = idx&3;
      const __half* ap;
      if (AMODE==0){
        ap = A + (size_t)(m0+row)*K + k0 + ch*8;
      } else {
        const int m = m0+row, b = m>>11, tt = m&2047;
        const int k = k0 + ch*8, dirr = k>>8, rr = k&255;
        ap = A + ((size_t)(dirr*2048 + tt)*16 + b)*256 + rr;
      }
      const int4 av = *(const int4*)ap;
      const int4 bv = *(const int4*)(B + (size_t)(n0+row)*K + k0 + ch*8);
      *(int4*)(As + row*40 + ch*8) = av;
      *(int4*)(Bs + row*40 + ch*8) = bv;
    }
    __syncthreads();
    half8_t af[4], bf[4];
    #pragma unroll
    for (int mi=0;mi<4;mi++) af[mi] = *(const half8_t*)(As + (wr*64+mi*16+lrow)*40 + lk*8);
    #pragma unroll
    for (int ni=0;ni<4;ni++) bf[ni] = *(const half8_t*)(Bs + (wc*64+ni*16+lrow)*40 + lk*8);
    #pragma unroll
    for (int mi=0;mi<4;mi++)
      #pragma unroll
      for (int ni=0;ni<4;ni++)
        acc[mi][ni] = __builtin_amdgcn_mfma_f32_16x16x32_f16(af[mi], bf[ni], acc[mi][ni], 0,0,0);
  }
  #pragma unroll
  for (int mi=0;mi<4;mi++){
    #pragma unroll
    for (int ni=0;ni<4;ni++){
      const int n = n0 + wc*64 + ni*16 + lrow;
      const float bv = bias[n];
      #pragma unroll
      for (int r2=0;r2<4;r2++){
        const int m = m0 + wr*64 + mi*16 + lk*4 + r2;
        float v = acc[mi][ni][r2] + bv;
        if (MODE==1){
          C[(size_t)m*256 + n] = __float2half(fmaxf(v, 0.f));
        } else {
          const int dir = n>>8, row = n&255;
          const int b = m>>11, t = m&2047;
          const size_t di = (((size_t)(dir*2048 + t)*64 + (row>>2))*16 + (size_t)b)*4 + (row&3);
          C[di] = __float2half(v);
        }
      }
    }
  }
}

// ---------------- recurrence via MFMA: one WG per direction, 16 chains ----------------
// preM: f16, idx = (((dir*T+t)*64 + rq)*16 + b)*4 + rr   (row = rq*4+rr)
// whh:  f16 [2][256 rows][256 k] row-major
// hblk: f16, idx = ((dir*2048+t)*16 + b)*256 + r   (coalesced per-step store)
// h LDS layout: element (k,b) at (k>>3)*128 + b*8 + (k&7)   (2-way bank alias = free)
__device__ __forceinline__ void rnn_step(
    const half8_t (&af)[4][8], uint2 (&P)[4],
    const uint2*& pp, long pstep, bool do_prefetch,
    const _Float16* cur, _Float16* nxt,
    __half*& op, long ostep,
    int wave, int lb, int lk)
{
  // accumulators: a0 init = pre (consumes P), a1 init = 0
  f32x4 a0[4], a1[4];
  #pragma unroll
  for (int mt=0;mt<4;++mt){
    H2x2 q = __builtin_bit_cast(H2x2, P[mt]);
    a0[mt] = (f32x4){(float)q.h[0][0], (float)q.h[0][1], (float)q.h[1][0], (float)q.h[1][1]};
    a1[mt] = (f32x4){0.f,0.f,0.f,0.f};
  }
  // prefetch pre for step t+2 into P (2-deep pipeline; never drained at barrier)
  if (do_prefetch){
    #pragma unroll
    for (int mt=0;mt<4;++mt) P[mt] = pp[mt*64];
    pp += pstep;
  }
  // B fragments for this step
  half8_t bf[8];
  #pragma unroll
  for (int kt=0;kt<8;++kt)
    bf[kt] = *(const half8_t*)(cur + (kt*4 + lk)*128 + lb*8);
  // MFMA: A read directly from AGPRs (no accvgpr_read traffic), 2 chains of 4
  accfence_pre(a0, a1);                       // VALU-write -> MFMA-SrcC wait states
  #pragma unroll
  for (int kt=0;kt<4;++kt){
    #pragma unroll
    for (int mt=0;mt<4;++mt){
      mfma_av(a0[mt], af[mt][kt],   bf[kt]);
      mfma_av(a1[mt], af[mt][kt+4], bf[kt+4]);
    }
  }
  accfence_post(a0, a1);                      // MFMA-write -> VALU-read wait states
  // tanh + emit
  #pragma unroll
  for (int mt=0;mt<4;++mt){
    float h[4];
    #pragma unroll
    for (int i=0;i<4;++i){
      const float u  = a0[mt][i] + a1[mt][i];
      const float e2 = fast_exp2f(u * 2.8853900817779268f);          // e^{2u}
      h[i] = fmaf(-2.f, __builtin_amdgcn_rcpf(1.f + e2), 1.f);       // tanh(u)
    }
    H2x2 pk2;
    pk2.h[0] = pkrtz(h[0], h[1]);                                    // 1 instr per pair
    pk2.h[1] = pkrtz(h[2], h[3]);
    const uint2 pv = __builtin_bit_cast(uint2, pk2);
    *(uint2*)(op + mt*16) = pv;                                      // coalesced global
    const int rw = wave*8 + mt*2 + (lk>>1);                          // next-step B-frag row
    *(uint2*)(nxt + rw*128 + lb*8 + (lk&1)*4) = pv;
  }
  op += ostep;
  // drain LDS only; global loads/stores stay in flight across the barrier
  asm volatile("s_waitcnt lgkmcnt(0)" ::: "memory");
  __builtin_amdgcn_s_barrier();
  __builtin_amdgcn_sched_barrier(0);
}

__global__ __launch_bounds__(256,1) void rnn_mfma_k(
    const __half* __restrict__ preM, const __half* __restrict__ whh,
    __half* __restrict__ hblk, int T)
{
  const int dir  = blockIdx.x;
  const int tid  = threadIdx.x;
  const int wave = tid>>6, lane = tid&63;
  const int lb = lane&15;   // batch (B-frag n / C col); also A-frag row
  const int lk = lane>>4;   // 0..3

  // A fragments: af[mt][kt] = W[wave*64+mt*16+lb][kt*32+lk*8 .. +7], homed in AGPRs
  half8_t af[4][8];
  {
    const __half* wp = whh + (size_t)dir*65536;
    #pragma unroll
    for (int mt=0;mt<4;++mt)
      #pragma unroll
      for (int kt=0;kt<8;++kt)
        af[mt][kt] = *(const half8_t*)(wp + (size_t)(wave*64 + mt*16 + lb)*256 + kt*32 + lk*8);
  }
  #pragma unroll
  for (int mt=0;mt<4;++mt)
    #pragma unroll
    for (int kt=0;kt<8;++kt) pinA(af[mt][kt]);

  // double-buffered h in B-fragment layout
  __shared__ __align__(16) _Float16 hbuf[2][4096];
  {
    uint4 z = {0u,0u,0u,0u};
    *(uint4*)(&hbuf[0][tid*16])     = z;
    *(uint4*)(&hbuf[0][tid*16 + 8]) = z;
  }

  const uint2* preu2 = (const uint2*)preM;
  const int poff = (wave*16 + lk)*16 + lb;     // within-step uint2 offset
  const long pstep = dir ? -1024L : 1024L;     // uint2 units per time step
  uint2 pA[4], pB[4];
  {
    const int tt0 = dir ? (T-1) : 0;
    const uint2* ps = preu2 + (size_t)(dir*T + tt0)*1024 + poff;
    #pragma unroll
    for (int mt=0;mt<4;++mt) pA[mt] = ps[mt*64];
  }
  {
    const int tt1 = dir ? (T-2) : 1;
    const uint2* ps = preu2 + (size_t)(dir*T + tt1)*1024 + poff;
    #pragma unroll
    for (int mt=0;mt<4;++mt) pB[mt] = ps[mt*64];
  }
  const uint2* pp = preu2 + (size_t)(dir*T + (dir ? T-3 : 2))*1024 + poff;

  const int tt0 = dir ? (T-1) : 0;
  __half* op = hblk + ((size_t)(dir*2048 + tt0)*16 + lb)*256 + wave*64 + lk*4;
  const long ostep = dir ? -4096L : 4096L;     // halves per time step

  __syncthreads();

  for (int t=0; t<T; t+=2){
    rnn_step(af, pA, pp, pstep, t+2<T, &hbuf[0][0], &hbuf[1][0], op, ostep, wave, lb, lk);
    rnn_step(af, pB, pp, pstep, t+3<T, &hbuf[1][0], &hbuf[0][0], op, ostep, wave, lb, lk);
  }
}

// ---------------- heads stage-2: y = z @ W2^T + b2 -> d_out (fp32) ----------------
// z: f16 [32768][256] (head1 cols 0..127, head2 cols 128..255)
// w2: f16 [64][128] (W2t1 rows 0..31, W2t2 rows 32..63); out: y1 then y2, each [m][32]
__global__ __launch_bounds__(256,4) void head2_k(
    const __half* __restrict__ z, const __half* __restrict__ w2,
    const float* __restrict__ by, float* __restrict__ yout)
{
  __shared__ _Float16 w2s[64*130];
  __shared__ __align__(16) _Float16 zs[4*256];
  const int tid = threadIdx.x;
  {
    const half2_t* g = (const half2_t*)w2;
    for (int idx=tid; idx<4096; idx+=256){
      int row=idx>>6, c=idx&63;
      *(half2_t*)(w2s + row*130 + c*2) = g[idx];
    }
  }
  const int m0 = blockIdx.x*4;
  if (tid < 128){
    const int4* g = (const int4*)(z + (size_t)m0*256);
    *(int4*)(zs + (tid>>5)*256 + (tid&31)*8) = g[tid];
  }
  __syncthreads();
  const int r = tid>>6, n = tid&63;
  const int head = n>>5;
  const half2_t* zp = (const half2_t*)(zs + r*256) + head*64;
  const half2_t* wp = (const half2_t*)(w2s + n*130);
  float acc0=by[n], acc1=0.f;
  #pragma unroll
  for (int j=0;j<64;j+=2){
    acc0 = fdot2f(zp[j],   wp[j],   acc0);
    acc1 = fdot2f(zp[j+1], wp[j+1], acc1);
  }
  yout[(size_t)head*1048576 + (size_t)(m0+r)*32 + (n&31)] = acc0+acc1;
}

extern "C" void kernel_launch(void* const* d_in, const int* in_sizes, int n_in,
                              void* d_out, int out_size, void* d_ws, size_t ws_size,
                              hipStream_t stream)
{
  (void)in_sizes; (void)n_in; (void)out_size; (void)ws_size;
  const float* X    =(const float*)d_in[0];
  const float* Wih0f=(const float*)d_in[1];
  const float* Whh0f=(const float*)d_in[2];
  const float* bih0f=(const float*)d_in[3];
  const float* bhh0f=(const float*)d_in[4];
  const float* Wih0b=(const float*)d_in[5];
  const float* Whh0b=(const float*)d_in[6];
  const float* bih0b=(const float*)d_in[7];
  const float* bhh0b=(const float*)d_in[8];
  const float* Wih1f=(const float*)d_in[9];
  const float* Whh1f=(const float*)d_in[10];
  const float* bih1f=(const float*)d_in[11];
  const float* bhh1f=(const float*)d_in[12];
  const float* Wih1b=(const float*)d_in[13];
  const float* Whh1b=(const float*)d_in[14];
  const float* bih1b=(const float*)d_in[15];
  const float* bhh1b=(const float*)d_in[16];
  const float* W1t1 =(const float*)d_in[17];
  const float* b1t1 =(const float*)d_in[18];
  const float* W2t1 =(const float*)d_in[19];
  const float* b2t1 =(const float*)d_in[20];
  const float* W1t2 =(const float*)d_in[21];
  const float* b1t2 =(const float*)d_in[22];
  const float* W2t2 =(const float*)d_in[23];
  const float* b2t2 =(const float*)d_in[24];

  char* ws = (char*)d_ws;
  size_t off = 0;
  auto alloc = [&](size_t bytes)->void*{ void* p = ws + off; off += (bytes + 1023) & ~(size_t)1023; return p; };
  __half* x16  = (__half*)alloc((size_t)4194304*2);
  __half* wih0 = (__half*)alloc((size_t)65536*2);
  __half* whh0 = (__half*)alloc((size_t)131072*2);
  __half* wih1 = (__half*)alloc((size_t)262144*2);
  __half* whh1 = (__half*)alloc((size_t)131072*2);
  __half* w1   = (__half*)alloc((size_t)131072*2);
  __half* w2   = (__half*)alloc((size_t)8192*2);
  float* b0 = (float*)alloc(512*4);
  float* b1 = (float*)alloc(512*4);
  float* bz = (float*)alloc(256*4);
  float* by = (float*)alloc(64*4);
  __half* preM  = (__half*)alloc((size_t)16777216*2); // shared: pre0 / pre1 / z
  __half* hblk0 = (__half*)alloc((size_t)16777216*2);
  __half* hblk1 = (__half*)alloc((size_t)16777216*2);

  PrepArgs pa;
  auto set=[&](int r, const float* s, __half* d, int n){ pa.src[r]=s; pa.dst[r]=d; pa.n[r]=n; };
  set(0, X, x16, 4194304);
  set(1, Wih0f, wih0, 32768);       set(2, Wih0b, wih0+32768, 32768);
  set(3, Whh0f, whh0, 65536);       set(4, Whh0b, whh0+65536, 65536);
  set(5, Wih1f, wih1, 131072);      set(6, Wih1b, wih1+131072, 131072);
  set(7, Whh1f, whh1, 65536);       set(8, Whh1b, whh1+65536, 65536);
  set(9, W1t1, w1, 65536);          set(10, W1t2, w1+65536, 65536);
  set(11, W2t1, w2, 4096);          set(12, W2t2, w2+4096, 4096);
  prep_cast_k<<<dim3(1024,13),256,0,stream>>>(pa);

  BiasArgs ba = {bih0f,bhh0f,bih0b,bhh0b,bih1f,bhh1f,bih1b,bhh1b,b1t1,b1t2,b2t1,b2t2,b0,b1,bz,by};
  prep_bias_k<<<1,256,0,stream>>>(ba);

  // layer 0
  gemm_nt_k<0,0><<<dim3(256,4),256,0,stream>>>(x16, wih0, preM, b0, 32768,512,128);
  rnn_mfma_k<<<2,256,0,stream>>>(preM, whh0, hblk0, 2048);
  // layer 1
  gemm_nt_k<1,0><<<dim3(256,4),256,0,stream>>>(hblk0, wih1, preM, b1, 32768,512,512);
  rnn_mfma_k<<<2,256,0,stream>>>(preM, whh1, hblk1, 2048);
  // heads
  gemm_nt_k<1,1><<<dim3(256,2),256,0,stream>>>(hblk1, w1, preM, bz, 32768,256,512);
  head2_k<<<8192,256,0,stream>>>(preM, w2, by, (float*)d_out);
}

// Round 12
// 2717.432 us; speedup vs baseline: 1.2568x; 1.2568x over previous
//
#include <hip/hip_runtime.h>
#include <hip/hip_fp16.h>

typedef _Float16 half2_t __attribute__((ext_vector_type(2)));
typedef _Float16 half8_t __attribute__((ext_vector_type(8)));
typedef float f32x4 __attribute__((ext_vector_type(4)));

struct __align__(16) H2x4 { half2_t h[4]; };
struct __align__(8)  H2x2 { half2_t h[2]; };

__device__ __forceinline__ float fdot2f(half2_t a, half2_t b, float c){
#if __has_builtin(__builtin_amdgcn_fdot2)
  return __builtin_amdgcn_fdot2(a, b, c, false);
#else
  return c + (float)a[0]*(float)b[0] + (float)a[1]*(float)b[1];
#endif
}

__device__ __forceinline__ float fast_exp2f(float x){
#if __has_builtin(__builtin_amdgcn_exp2f)
  return __builtin_amdgcn_exp2f(x);
#else
  return __expf(x*0.6931471805599453f);
#endif
}

// Pack two f32 -> packed f16 pair (v_cvt_pkrtz_f16_f32), bit-cast to our type.
__device__ __forceinline__ half2_t pkrtz(float lo, float hi){
  return __builtin_bit_cast(half2_t, __builtin_amdgcn_cvt_pkrtz(lo, hi));
}

// Pin a fragment into an ACCUMULATOR register (AGPR): legal long-term home for
// loop-invariant weights on gfx950 (unified file; MFMA reads A from AGPR).
__device__ __forceinline__ void pinA(half8_t &x){ asm volatile("" : "+a"(x)); }

// MFMA with A sourced from AGPR, B from VGPR, C/D in VGPR.
// Raw asm bypasses the MFMA hazard recognizer — accumulator reads must be
// fenced with wait-state nops (accfence_*) before VALU consumption.
__device__ __forceinline__ void mfma_av(f32x4 &c, const half8_t &a, const half8_t &b){
  asm("v_mfma_f32_16x16x32_f16 %0, %1, %2, %0"
      : "+v"(c) : "a"(a), "v"(b));
}

// VALU-write -> MFMA-SrcC wait states (covers all accumulators).
__device__ __forceinline__ void accfence_pre(f32x4 (&a0)[2], f32x4 (&a1)[2]){
  asm volatile("s_nop 1"
    : "+v"(a0[0]),"+v"(a0[1]),"+v"(a1[0]),"+v"(a1[1]));
}
// MFMA-write -> VALU-read wait states for ONE row-group.
__device__ __forceinline__ void accfence_grp(f32x4 &x, f32x4 &y){
  asm volatile("s_nop 7\n\ts_nop 7" : "+v"(x), "+v"(y));
}

// ---------------- prep: fp32 -> f16 casts ----------------
struct PrepArgs {
  const float* src[13];
  __half* dst[13];
  int n[13];
};
__global__ __launch_bounds__(256) void prep_cast_k(PrepArgs a){
  const int r = blockIdx.y;
  const int n = a.n[r];
  const float* __restrict__ s = a.src[r];
  __half* __restrict__ d = a.dst[r];
  for (int i = blockIdx.x*256 + threadIdx.x; i < n; i += gridDim.x*256)
    d[i] = __float2half(s[i]);
}

struct BiasArgs {
  const float *bih0f,*bhh0f,*bih0b,*bhh0b,*bih1f,*bhh1f,*bih1b,*bhh1b;
  const float *b1t1,*b1t2,*b2t1,*b2t2;
  float *b0,*b1,*bz,*by;
};
__global__ __launch_bounds__(256) void prep_bias_k(BiasArgs a){
  const int i = threadIdx.x;
  if (i < 256){
    a.b0[i]     = a.bih0f[i] + a.bhh0f[i];
    a.b0[256+i] = a.bih0b[i] + a.bhh0b[i];
    a.b1[i]     = a.bih1f[i] + a.bhh1f[i];
    a.b1[256+i] = a.bih1b[i] + a.bhh1b[i];
  }
  if (i < 128){ a.bz[i] = a.b1t1[i]; a.bz[128+i] = a.b1t2[i]; }
  if (i < 32){  a.by[i] = a.b2t1[i]; a.by[32+i]  = a.b2t2[i]; }
}

// ---------------- GEMM: C[m][n] = sum_k A[m][k]*B[n][k] + bias[n] ----------------
// B: f16 [N][K] row-major (weight layout).
// AMODE 0: A plain f16 [M][K] row-major.
// AMODE 1: A is rnn hblk layout: element (m,k) with m=b*2048+t, k=dir*256+r at
//          A[((dir*2048+t)*16 + b)*256 + r].
// MODE 0: out = pre layout for rnn_mfma_k:
//          idx = (((dir*2048+t)*64 + (row>>2))*16 + b)*4 + (row&3), dir=n>>8,row=n&255.
// MODE 1: out = z layout [m][256], relu.
template<int AMODE, int MODE>
__global__ __launch_bounds__(256,2) void gemm_nt_k(
    const __half* __restrict__ A, const __half* __restrict__ B,
    __half* __restrict__ C, const float* __restrict__ bias,
    int M, int N, int K)
{
  __shared__ __align__(16) _Float16 As[128*40];
  __shared__ __align__(16) _Float16 Bs[128*40];
  const int tid = threadIdx.x;
  const int wave = tid>>6, lane = tid&63;
  const int wr = wave>>1, wc = wave&1;
  const int lrow = lane&15, lk = lane>>4;
  const int m0 = blockIdx.x*128, n0 = blockIdx.y*128;
  f32x4 acc[4][4];
  #pragma unroll
  for (int i=0;i<4;i++)
    #pragma unroll
    for (int j=0;j<4;j++) acc[i][j] = (f32x4){0.f,0.f,0.f,0.f};

  for (int k0=0; k0<K; k0+=32){
    __syncthreads();
    #pragma unroll
    for (int i=0;i<2;i++){
      int idx = i*256 + tid;
      int row = idx>>2, ch = idx&3;
      const __half* ap;
      if (AMODE==0){
        ap = A + (size_t)(m0+row)*K + k0 + ch*8;
      } else {
        const int m = m0+row, b = m>>11, tt = m&2047;
        const int k = k0 + ch*8, dirr = k>>8, rr = k&255;
        ap = A + ((size_t)(dirr*2048 + tt)*16 + b)*256 + rr;
      }
      const int4 av = *(const int4*)ap;
      const int4 bv = *(const int4*)(B + (size_t)(n0+row)*K + k0 + ch*8);
      *(int4*)(As + row*40 + ch*8) = av;
      *(int4*)(Bs + row*40 + ch*8) = bv;
    }
    __syncthreads();
    half8_t af[4], bf[4];
    #pragma unroll
    for (int mi=0;mi<4;mi++) af[mi] = *(const half8_t*)(As + (wr*64+mi*16+lrow)*40 + lk*8);
    #pragma unroll
    for (int ni=0;ni<4;ni++) bf[ni] = *(const half8_t*)(Bs + (wc*64+ni*16+lrow)*40 + lk*8);
    #pragma unroll
    for (int mi=0;mi<4;mi++)
      #pragma unroll
      for (int ni=0;ni<4;ni++)
        acc[mi][ni] = __builtin_amdgcn_mfma_f32_16x16x32_f16(af[mi], bf[ni], acc[mi][ni], 0,0,0);
  }
  #pragma unroll
  for (int mi=0;mi<4;mi++){
    #pragma unroll
    for (int ni=0;ni<4;ni++){
      const int n = n0 + wc*64 + ni*16 + lrow;
      const float bv = bias[n];
      #pragma unroll
      for (int r2=0;r2<4;r2++){
        const int m = m0 + wr*64 + mi*16 + lk*4 + r2;
        float v = acc[mi][ni][r2] + bv;
        if (MODE==1){
          C[(size_t)m*256 + n] = __float2half(fmaxf(v, 0.f));
        } else {
          const int dir = n>>8, row = n&255;
          const int b = m>>11, t = m&2047;
          const size_t di = (((size_t)(dir*2048 + t)*64 + (row>>2))*16 + (size_t)b)*4 + (row&3);
          C[di] = __float2half(v);
        }
      }
    }
  }
}

// ---------------- recurrence via MFMA: one WG (8 waves) per direction ----------------
// preM: f16, idx = (((dir*T+t)*64 + rq)*16 + b)*4 + rr   (row = rq*4+rr)
// whh:  f16 [2][256 rows][256 k] row-major
// hblk: f16, idx = ((dir*2048+t)*16 + b)*256 + r   (coalesced per-step store)
// h LDS layout: element (k,b) at (k>>3)*128 + b*8 + (k&7)
// Each wave owns 32 rows (2 groups of 16); 2 waves/SIMD so one wave's tanh
// overlaps the other's MFMA (m114: separate pipes co-schedule across waves).
__device__ __forceinline__ void rnn_step(
    const half8_t (&af)[2][8], uint2 (&P)[2],
    const uint2*& pp, long pstep, bool do_prefetch,
    const _Float16* cur, _Float16* nxt,
    __half*& op, long ostep,
    int wave, int lb, int lk)
{
  // accumulators: a0 init = pre (consumes P), a1 init = 0
  f32x4 a0[2], a1[2];
  #pragma unroll
  for (int mt=0;mt<2;++mt){
    H2x2 q = __builtin_bit_cast(H2x2, P[mt]);
    a0[mt] = (f32x4){(float)q.h[0][0], (float)q.h[0][1], (float)q.h[1][0], (float)q.h[1][1]};
    a1[mt] = (f32x4){0.f,0.f,0.f,0.f};
  }
  // prefetch pre for step t+2 into P (2-deep pipeline; never drained at barrier)
  if (do_prefetch){
    P[0] = pp[0];
    P[1] = pp[64];
    pp += pstep;
  }
  // B fragments for this step (full K=256 per wave)
  half8_t bf[8];
  #pragma unroll
  for (int kt=0;kt<8;++kt)
    bf[kt] = *(const half8_t*)(cur + (kt*4 + lk)*128 + lb*8);

  accfence_pre(a0, a1);                       // VALU-write -> MFMA-SrcC wait states
  // issue BOTH groups' MFMAs before consuming either (grp1 covers grp0 latency)
  #pragma unroll
  for (int kt=0;kt<4;++kt){
    mfma_av(a0[0], af[0][kt],   bf[kt]);
    mfma_av(a1[0], af[0][kt+4], bf[kt+4]);
  }
  #pragma unroll
  for (int kt=0;kt<4;++kt){
    mfma_av(a0[1], af[1][kt],   bf[kt]);
    mfma_av(a1[1], af[1][kt+4], bf[kt+4]);
  }
  // finish group 0 while group 1 is still in the matrix pipe, then group 1
  #pragma unroll
  for (int mt=0;mt<2;++mt){
    if (mt==0) accfence_grp(a0[0], a1[0]);    // MFMA-write -> VALU-read wait states
    else       accfence_grp(a0[1], a1[1]);
    float h[4];
    #pragma unroll
    for (int i=0;i<4;++i){
      const float u  = a0[mt][i] + a1[mt][i];
      const float e2 = fast_exp2f(u * 2.8853900817779268f);          // e^{2u}
      h[i] = fmaf(-2.f, __builtin_amdgcn_rcpf(1.f + e2), 1.f);       // tanh(u)
    }
    H2x2 pk2;
    pk2.h[0] = pkrtz(h[0], h[1]);
    pk2.h[1] = pkrtz(h[2], h[3]);
    const uint2 pv = __builtin_bit_cast(uint2, pk2);
    *(uint2*)(op + mt*16) = pv;                                      // coalesced global
    const int rw = wave*4 + mt*2 + (lk>>1);                          // next-step B-frag row
    *(uint2*)(nxt + rw*128 + lb*8 + (lk&1)*4) = pv;
  }
  op += ostep;
  // drain LDS only; global loads/stores stay in flight across the barrier
  asm volatile("s_waitcnt lgkmcnt(0)" ::: "memory");
  __builtin_amdgcn_s_barrier();
  __builtin_amdgcn_sched_barrier(0);
}

__global__ __launch_bounds__(512,2) void rnn_mfma_k(
    const __half* __restrict__ preM, const __half* __restrict__ whh,
    __half* __restrict__ hblk, int T)
{
  const int dir  = blockIdx.x;
  const int tid  = threadIdx.x;
  const int wave = tid>>6, lane = tid&63;
  const int lb = lane&15;   // batch (B-frag n / C col); also A-frag row
  const int lk = lane>>4;   // 0..3

  // A fragments: af[mt][kt] = W[wave*32+mt*16+lb][kt*32+lk*8 .. +7], homed in AGPRs
  half8_t af[2][8];
  {
    const __half* wp = whh + (size_t)dir*65536;
    #pragma unroll
    for (int mt=0;mt<2;++mt)
      #pragma unroll
      for (int kt=0;kt<8;++kt)
        af[mt][kt] = *(const half8_t*)(wp + (size_t)(wave*32 + mt*16 + lb)*256 + kt*32 + lk*8);
  }
  #pragma unroll
  for (int mt=0;mt<2;++mt)
    #pragma unroll
    for (int kt=0;kt<8;++kt) pinA(af[mt][kt]);

  // double-buffered h in B-fragment layout
  __shared__ __align__(16) _Float16 hbuf[2][4096];
  {
    uint4 z = {0u,0u,0u,0u};
    *(uint4*)(&hbuf[0][tid*8]) = z;              // 512 threads x 8 halves = 4096
  }

  const uint2* preu2 = (const uint2*)preM;
  const int poff = (wave*8 + lk)*16 + lb;      // within-step uint2 offset (rq*16+b)
  const long pstep = dir ? -1024L : 1024L;     // uint2 units per time step
  uint2 pA[2], pB[2];
  {
    const int tt0 = dir ? (T-1) : 0;
    const uint2* ps = preu2 + (size_t)(dir*T + tt0)*1024 + poff;
    pA[0] = ps[0]; pA[1] = ps[64];
  }
  {
    const int tt1 = dir ? (T-2) : 1;
    const uint2* ps = preu2 + (size_t)(dir*T + tt1)*1024 + poff;
    pB[0] = ps[0]; pB[1] = ps[64];
  }
  const uint2* pp = preu2 + (size_t)(dir*T + (dir ? T-3 : 2))*1024 + poff;

  const int tt0 = dir ? (T-1) : 0;
  __half* op = hblk + ((size_t)(dir*2048 + tt0)*16 + lb)*256 + wave*32 + lk*4;
  const long ostep = dir ? -4096L : 4096L;     // halves per time step

  __syncthreads();

  for (int t=0; t<T; t+=2){
    rnn_step(af, pA, pp, pstep, t+2<T, &hbuf[0][0], &hbuf[1][0], op, ostep, wave, lb, lk);
    rnn_step(af, pB, pp, pstep, t+3<T, &hbuf[1][0], &hbuf[0][0], op, ostep, wave, lb, lk);
  }
}

// ---------------- heads stage-2: y = z @ W2^T + b2 -> d_out (fp32) ----------------
// z: f16 [32768][256] (head1 cols 0..127, head2 cols 128..255)
// w2: f16 [64][128] (W2t1 rows 0..31, W2t2 rows 32..63); out: y1 then y2, each [m][32]
__global__ __launch_bounds__(256,4) void head2_k(
    const __half* __restrict__ z, const __half* __restrict__ w2,
    const float* __restrict__ by, float* __restrict__ yout)
{
  __shared__ _Float16 w2s[64*130];
  __shared__ __align__(16) _Float16 zs[4*256];
  const int tid = threadIdx.x;
  {
    const half2_t* g = (const half2_t*)w2;
    for (int idx=tid; idx<4096; idx+=256){
      int row=idx>>6, c=idx&63;
      *(half2_t*)(w2s + row*130 + c*2) = g[idx];
    }
  }
  const int m0 = blockIdx.x*4;
  if (tid < 128){
    const int4* g = (const int4*)(z + (size_t)m0*256);
    *(int4*)(zs + (tid>>5)*256 + (tid&31)*8) = g[tid];
  }
  __syncthreads();
  const int r = tid>>6, n = tid&63;
  const int head = n>>5;
  const half2_t* zp = (const half2_t*)(zs + r*256) + head*64;
  const half2_t* wp = (const half2_t*)(w2s + n*130);
  float acc0=by[n], acc1=0.f;
  #pragma unroll
  for (int j=0;j<64;j+=2){
    acc0 = fdot2f(zp[j],   wp[j],   acc0);
    acc1 = fdot2f(zp[j+1], wp[j+1], acc1);
  }
  yout[(size_t)head*1048576 + (size_t)(m0+r)*32 + (n&31)] = acc0+acc1;
}

extern "C" void kernel_launch(void* const* d_in, const int* in_sizes, int n_in,
                              void* d_out, int out_size, void* d_ws, size_t ws_size,
                              hipStream_t stream)
{
  (void)in_sizes; (void)n_in; (void)out_size; (void)ws_size;
  const float* X    =(const float*)d_in[0];
  const float* Wih0f=(const float*)d_in[1];
  const float* Whh0f=(const float*)d_in[2];
  const float* bih0f=(const float*)d_in[3];
  const float* bhh0f=(const float*)d_in[4];
  const float* Wih0b=(const float*)d_in[5];
  const float* Whh0b=(const float*)d_in[6];
  const float* bih0b=(const float*)d_in[7];
  const float* bhh0b=(const float*)d_in[8];
  const float* Wih1f=(const float*)d_in[9];
  const float* Whh1f=(const float*)d_in[10];
  const float* bih1f=(const float*)d_in[11];
  const float* bhh1f=(const float*)d_in[12];
  const float* Wih1b=(const float*)d_in[13];
  const float* Whh1b=(const float*)d_in[14];
  const float* bih1b=(const float*)d_in[15];
  const float* bhh1b=(const float*)d_in[16];
  const float* W1t1 =(const float*)d_in[17];
  const float* b1t1 =(const float*)d_in[18];
  const float* W2t1 =(const float*)d_in[19];
  const float* b2t1 =(const float*)d_in[20];
  const float* W1t2 =(const float*)d_in[21];
  const float* b1t2 =(const float*)d_in[22];
  const float* W2t2 =(const float*)d_in[23];
  const float* b2t2 =(const float*)d_in[24];

  char* ws = (char*)d_ws;
  size_t off = 0;
  auto alloc = [&](size_t bytes)->void*{ void* p = ws + off; off += (bytes + 1023) & ~(size_t)1023; return p; };
  __half* x16  = (__half*)alloc((size_t)4194304*2);
  __half* wih0 = (__half*)alloc((size_t)65536*2);
  __half* whh0 = (__half*)alloc((size_t)131072*2);
  __half* wih1 = (__half*)alloc((size_t)262144*2);
  __half* whh1 = (__half*)alloc((size_t)131072*2);
  __half* w1   = (__half*)alloc((size_t)131072*2);
  __half* w2   = (__half*)alloc((size_t)8192*2);
  float* b0 = (float*)alloc(512*4);
  float* b1 = (float*)alloc(512*4);
  float* bz = (float*)alloc(256*4);
  float* by = (float*)alloc(64*4);
  __half* preM  = (__half*)alloc((size_t)16777216*2); // shared: pre0 / pre1 / z
  __half* hblk0 = (__half*)alloc((size_t)16777216*2);
  __half* hblk1 = (__half*)alloc((size_t)16777216*2);

  PrepArgs pa;
  auto set=[&](int r, const float* s, __half* d, int n){ pa.src[r]=s; pa.dst[r]=d; pa.n[r]=n; };
  set(0, X, x16, 4194304);
  set(1, Wih0f, wih0, 32768);       set(2, Wih0b, wih0+32768, 32768);
  set(3, Whh0f, whh0, 65536);       set(4, Whh0b, whh0+65536, 65536);
  set(5, Wih1f, wih1, 131072);      set(6, Wih1b, wih1+131072, 131072);
  set(7, Whh1f, whh1, 65536);       set(8, Whh1b, whh1+65536, 65536);
  set(9, W1t1, w1, 65536);          set(10, W1t2, w1+65536, 65536);
  set(11, W2t1, w2, 4096);          set(12, W2t2, w2+4096, 4096);
  prep_cast_k<<<dim3(1024,13),256,0,stream>>>(pa);

  BiasArgs ba = {bih0f,bhh0f,bih0b,bhh0b,bih1f,bhh1f,bih1b,bhh1b,b1t1,b1t2,b2t1,b2t2,b0,b1,bz,by};
  prep_bias_k<<<1,256,0,stream>>>(ba);

  // layer 0
  gemm_nt_k<0,0><<<dim3(256,4),256,0,stream>>>(x16, wih0, preM, b0, 32768,512,128);
  rnn_mfma_k<<<2,512,0,stream>>>(preM, whh0, hblk0, 2048);
  // layer 1
  gemm_nt_k<1,0><<<dim3(256,4),256,0,stream>>>(hblk0, wih1, preM, b1, 32768,512,512);
  rnn_mfma_k<<<2,512,0,stream>>>(preM, whh1, hblk1, 2048);
  // heads
  gemm_nt_k<1,1><<<dim3(256,2),256,0,stream>>>(hblk1, w1, preM, bz, 32768,256,512);
  head2_k<<<8192,256,0,stream>>>(preM, w2, by, (float*)d_out);
}